// Round 2
// baseline (963.748 us; speedup 1.0000x reference)
//
#include <hip/hip_runtime.h>
#include <stdint.h>

typedef unsigned int u32;
typedef unsigned long long u64;

#define BN 32
#define NN 1024
#define DD 32
#define KK 204
#define NBIN 2048

#define X_ELEMS (BN * NN * DD)            /* 1048576  */
#define E_EDGES (BN * NN * KK)            /* 6684672  */
#define SRC_BASE (X_ELEMS)                /* fp32 idx 1048576  */
#define DST_BASE (X_ELEMS + E_EDGES)      /* fp32 idx 7733248  */
#define EMB_BASE (X_ELEMS + 2 * E_EDGES)  /* fp32 idx 14417920 */

__global__ __launch_bounds__(256) void edge_kernel(
    const float2* __restrict__ locs,     // B*N float2
    const float4* __restrict__ emb_in,   // B*N*D floats as float4
    const float*  __restrict__ Wp,       // 32 floats (W[d][0])
    const float*  __restrict__ bp,       // 32 floats
    float* __restrict__ out)
{
#pragma clang fp contract(off)
    __shared__ u32 hist[NBIN];
    __shared__ u32 psum[256];
    __shared__ u64 comp[256];
    __shared__ float sW[DD], sB[DD];
    __shared__ float sdist[KK];
    __shared__ u32 sT, sCnt;

    const int tid = threadIdx.x;
    const int row = blockIdx.x;          // b*N + i
    const int bb  = row >> 10;
    const u32 bOff = (u32)(bb << 10);
    const int ii  = row & 1023;
    const float rowf = (float)row;

    float4* out4 = (float4*)out;

    // ---- x passthrough: 8 float4 per row
    if (tid < DD / 4)
        out4[(u32)row * (DD / 4) + tid] = emb_in[(u32)row * (DD / 4) + tid];

    // ---- src column: 204 copies of rowf (51 float4)
    if (tid < KK / 4)
        out4[SRC_BASE / 4 + (u32)row * (KK / 4) + tid] =
            make_float4(rowf, rowf, rowf, rowf);

    // ---- LDS init
    for (int q = tid; q < NBIN; q += 256) hist[q] = 0;
    if (tid < DD) { sW[tid] = Wp[tid]; sB[tid] = bp[tid]; }
    if (tid == 0) sCnt = 0;
    comp[tid] = ~0ull;

    // ---- own location
    float2 myloc = locs[row];
    __syncthreads();

    // ---- distances, keys, histogram (4 points/thread)
    float dist_r[4];
    u64   key_r[4];
#pragma unroll
    for (int c = 0; c < 4; ++c) {
        int j = tid + c * 256;
        float2 lj = locs[bOff + (u32)j];
        float dx = myloc.x - lj.x;
        float dy = myloc.y - lj.y;
        float sq = dx * dx + dy * dy;      // contract(off): mul,mul,add like numpy
        float d  = __fsqrt_rn(sq);         // correctly rounded like np.sqrt
        dist_r[c] = d;
        if (j == ii) {
            key_r[c] = ~0ull;              // self-loop excluded
        } else {
            union { float f; u32 i; } uu; uu.f = d;
            key_r[c] = (((u64)uu.i) << 10) | (u32)j;   // (dist, idx) lexicographic
            int bin = (int)(d * 1024.0f);
            bin = bin > (NBIN - 1) ? (NBIN - 1) : bin;
            atomicAdd(&hist[bin], 1u);
        }
    }
    __syncthreads();

    // ---- scan histogram (8 bins/thread), find bin T containing the 204th
    u32 s = 0;
#pragma unroll
    for (int q = 0; q < 8; ++q) s += hist[tid * 8 + q];
    u32 v = s;
    psum[tid] = v;
    __syncthreads();
    for (int off = 1; off < 256; off <<= 1) {
        u32 o = (tid >= off) ? psum[tid - off] : 0;
        __syncthreads();
        v += o; psum[tid] = v;
        __syncthreads();
    }
    u32 excl = v - s;
    if (excl < KK && v >= KK) {            // exactly one thread
        u32 cum = excl;
#pragma unroll
        for (int q = 0; q < 8; ++q) {
            u32 c = hist[tid * 8 + q];
            if (cum + c >= KK) { sT = (u32)(tid * 8 + q); break; }
            cum += c;
        }
    }
    __syncthreads();
    const u32 T = sT;

    // ---- gather candidates with bin <= T (superset of top-204, ~206 typ.)
#pragma unroll
    for (int c = 0; c < 4; ++c) {
        if (key_r[c] != ~0ull) {
            int bin = (int)(dist_r[c] * 1024.0f);
            bin = bin > (NBIN - 1) ? (NBIN - 1) : bin;
            if ((u32)bin <= T) {
                u32 pos = atomicAdd(&sCnt, 1u);
                if (pos < 256) comp[pos] = key_r[c];
            }
        }
    }
    __syncthreads();

    // ---- bitonic sort 256 u64 keys ascending
    for (int k = 2; k <= 256; k <<= 1) {
        for (int j = k >> 1; j > 0; j >>= 1) {
            int l = tid ^ j;
            if (l > tid) {
                u64 a = comp[tid], b2 = comp[l];
                bool up = ((tid & k) == 0);
                if ((a > b2) == up) { comp[tid] = b2; comp[l] = a; }
            }
            __syncthreads();
        }
    }

    // ---- unpack distances; dst column (51 float4)
    if (tid < KK) {
        union { u32 i; float f; } uu; uu.i = (u32)(comp[tid] >> 10);
        sdist[tid] = uu.f;
    }
    if (tid < KK / 4) {
        u32 i0 = (u32)(comp[4 * tid]     & 1023u) + bOff;
        u32 i1 = (u32)(comp[4 * tid + 1] & 1023u) + bOff;
        u32 i2 = (u32)(comp[4 * tid + 2] & 1023u) + bOff;
        u32 i3 = (u32)(comp[4 * tid + 3] & 1023u) + bOff;
        out4[DST_BASE / 4 + (u32)row * (KK / 4) + tid] =
            make_float4((float)i0, (float)i1, (float)i2, (float)i3);
    }
    __syncthreads();

    // ---- edge_attr_emb: emb[e][d] = dist*W[d] + b[d], float4 over d
    {
        const float4* W4 = (const float4*)sW;
        const float4* B4 = (const float4*)sB;
        u32 rowBase4 = EMB_BASE / 4 + (u32)row * (KK * DD / 4);
        for (int q = tid; q < KK * DD / 4; q += 256) {   // 1632 float4/row
            int j = q >> 3;
            int p = q & 7;
            float dv = sdist[j];
            float4 w = W4[p], bb4 = B4[p];
            out4[rowBase4 + q] = make_float4(dv * w.x + bb4.x,
                                             dv * w.y + bb4.y,
                                             dv * w.z + bb4.z,
                                             dv * w.w + bb4.w);
        }
    }
}

extern "C" void kernel_launch(void* const* d_in, const int* in_sizes, int n_in,
                              void* d_out, int out_size, void* d_ws, size_t ws_size,
                              hipStream_t stream) {
    const float2* locs = (const float2*)d_in[0];
    const float4* emb  = (const float4*)d_in[1];
    const float*  W    = (const float*)d_in[2];
    const float*  b    = (const float*)d_in[3];
    float* out = (float*)d_out;
    hipLaunchKernelGGL(edge_kernel, dim3(BN * NN), dim3(256), 0, stream,
                       locs, emb, W, b, out);
}